// Round 4
// baseline (414.633 us; speedup 1.0000x reference)
//
#include <hip/hip_runtime.h>
#include <cmath>

#define S_   4
#define DIN  1024
#define D_   256
#define B_   4
#define T_   4096
#define BT_  (B_*T_)
#define GN   (S_*3*D_)     // 3072 concat N for the big GEMM
#define CHUNKS 128
#define CL   (T_/CHUNKS)   // 32

typedef short bf16x8 __attribute__((ext_vector_type(8)));
typedef float f32x4  __attribute__((ext_vector_type(4)));

struct SC { float are[S_]; float aim[S_]; float bsc[S_]; };

__device__ inline unsigned short f2bf(float f) {
    unsigned int u = __builtin_bit_cast(unsigned int, f);
    unsigned int r = (u + 0x7FFFu + ((u >> 16) & 1u)) >> 16;
    return (unsigned short)r;
}
__device__ inline float bf2f_lo(unsigned int u) {
    return __builtin_bit_cast(float, u << 16);
}
__device__ inline float bf2f_hi(unsigned int u) {
    return __builtin_bit_cast(float, u & 0xFFFF0000u);
}
// omg u16 fixed-point decode: (u + 0.5) / 65536
__device__ inline float u16om(unsigned int u) {
    return ((float)u + 0.5f) * (1.f/65536.f);
}

#define GLD_LDS(gp, lp) \
    __builtin_amdgcn_global_load_lds( \
        (const __attribute__((address_space(1))) void*)(gp), \
        (__attribute__((address_space(3))) void*)(lp), 16, 0, 0)

// ---------------------------------------------------------------------------
// x fp32 -> bf16
// ---------------------------------------------------------------------------
__global__ __launch_bounds__(256) void kconv_x(
    const float* __restrict__ x, unsigned short* __restrict__ xb)
{
    const size_t i = ((size_t)blockIdx.x*256 + threadIdx.x)*4;
    const float4 v = *(const float4*)(x + i);
    ushort4 o;
    o.x = f2bf(v.x); o.y = f2bf(v.y); o.z = f2bf(v.z); o.w = f2bf(v.w);
    *(ushort4*)(xb + i) = o;
}

// ---------------------------------------------------------------------------
// Weight transpose+convert (Wg2 only): src [S][K][N] fp32 -> [S][N][K] bf16
// ---------------------------------------------------------------------------
__global__ __launch_bounds__(256) void kconv_w(
    const float* __restrict__ src, unsigned short* __restrict__ dst,
    int K, int N, size_t dst_s_stride)
{
    __shared__ float t[32][33];
    const int k0 = blockIdx.x*32, n0 = blockIdx.y*32, s = blockIdx.z;
    const float* sp = src + (size_t)s*K*N;
    unsigned short* dp = dst + (size_t)s*dst_s_stride;
    const int c = threadIdx.x & 31, r0 = threadIdx.x >> 5;
    #pragma unroll
    for (int p = 0; p < 4; ++p)
        t[r0 + p*8][c] = sp[(size_t)(k0 + r0 + p*8)*N + n0 + c];
    __syncthreads();
    #pragma unroll
    for (int p = 0; p < 4; ++p)
        dp[(size_t)(n0 + r0 + p*8)*K + k0 + c] = f2bf(t[c][r0 + p*8]);
}

// ---------------------------------------------------------------------------
// Merged transpose+convert for the three DIN x D_ weights -> Bct layout.
// z = widx*S_ + s; widx 0:Wg1 1:Wdr 2:Wdi
// ---------------------------------------------------------------------------
__global__ __launch_bounds__(256) void kconv_w3(
    const float* __restrict__ Wg1, const float* __restrict__ Wdr,
    const float* __restrict__ Wdi, unsigned short* __restrict__ dst)
{
    __shared__ float t[32][33];
    const int z = blockIdx.z;
    const int widx = z >> 2, s = z & 3;
    const float* src = (widx == 0) ? Wg1 : ((widx == 1) ? Wdr : Wdi);
    const float* sp = src + (size_t)s*DIN*D_;
    unsigned short* dp = dst + (size_t)s*768*DIN + (size_t)widx*D_*DIN;
    const int k0 = blockIdx.x*32, n0 = blockIdx.y*32;
    const int c = threadIdx.x & 31, r0 = threadIdx.x >> 5;
    #pragma unroll
    for (int p = 0; p < 4; ++p)
        t[r0 + p*8][c] = sp[(size_t)(k0 + r0 + p*8)*D_ + n0 + c];
    __syncthreads();
    #pragma unroll
    for (int p = 0; p < 4; ++p)
        dp[(size_t)(n0 + r0 + p*8)*DIN + k0 + c] = f2bf(t[c][r0 + p*8]);
}

// ---------------------------------------------------------------------------
// k1_8p: C[16384][3072] = xb * Bct^T, 256x256 tile, BK=64, 8 waves (2M x 4N),
// 8-phase schedule, counted vmcnt (never 0 in steady state), st-swizzled LDS.
// LDS: 8 half-tile slots of 16 KiB: [buf][op][half] (128 rows x 64 k bf16).
// R4 change: NO manual lgkmcnt(0) before MFMA. Reads are plain C++ loads and
// the kernel has no ds_writes, so the compiler emits exact counted lgkmcnt
// per MFMA operand. Reads grouped by k-slice (6+6) and MFMA kk-outer: the
// first 8 MFMAs wait only on 6 reads; the other 6 drain under them.
// Issue schedule: P1:A1[t+1] P2:B0[t+1] P3:A0[t+2] P4:B1[t+2]
//                 P5:A1[t+2] P6:B0[t+2] P7:A0[t+3] P8:B1[t+3]
// Waits: vmcnt(4) at P4 and P8, vmcnt(0) in the last iteration.
// ---------------------------------------------------------------------------
template<bool DRVB>
__global__ __launch_bounds__(512, 2) void k1_8p(
    const unsigned short* __restrict__ xb,
    const unsigned short* __restrict__ Bct,
    const float* __restrict__ bg1, const float* __restrict__ bdr,
    const float* __restrict__ bdi,
    unsigned short* __restrict__ g1b,
    unsigned short* __restrict__ drvb, float* __restrict__ drvf)
{
    __shared__ unsigned short L[8*8192];   // 128 KiB

    const int tid  = threadIdx.x;
    const int wave = tid >> 6, lane = tid & 63;
    const int wmr  = wave >> 2;            // 0..1  (64-row group within a half)
    const int wnr  = wave & 3;             // 0..3  (32-col group within a half)
    const int row0 = blockIdx.x * 256, col0 = blockIdx.y * 256;
    const int cn = lane & 15, quad = lane >> 4;
    const int e8 = cn & 7;
    const int srow = lane >> 3;                    // staging row-in-8
    const int lksw = ((lane & 7) ^ srow) * 8;      // pre-swizzled src k offset

    const unsigned short* Ag = xb  + (size_t)row0 * DIN;
    const unsigned short* Bg = Bct + (size_t)col0 * DIN;

    f32x4 acc[8][4];
    const f32x4 z = {0.f, 0.f, 0.f, 0.f};
    #pragma unroll
    for (int i = 0; i < 8; ++i)
        #pragma unroll
        for (int j = 0; j < 4; ++j) acc[i][j] = z;

#define SLOT(b,o,h) (L + (((b)*4 + (o)*2 + (h)) * 8192))
// stage one 128x64 half-tile (2 x global_load_lds per thread-wave)
#define STAGE(b,o,h,kt,Gp) do { \
    const unsigned short* _g = (Gp) + (size_t)((h)*128 + wave*8 + srow)*DIN \
                             + (size_t)(kt)*64 + lksw; \
    unsigned short* _l = SLOT(b,o,h) + wave*512; \
    GLD_LDS(_g, _l); \
    GLD_LDS(_g + (size_t)64*DIN, _l + 4096); \
} while(0)

#define PHASE(b, ih, jh, STG, WT) do { \
    bf16x8 af[4][2], bfv[2][2]; \
    /* reads grouped by k-slice: kk0 batch (6), then kk1 batch (6) */ \
    _Pragma("unroll") \
    for (int kk = 0; kk < 2; ++kk) { \
        _Pragma("unroll") \
        for (int ii = 0; ii < 4; ++ii) \
            af[ii][kk] = *(const bf16x8*)(SLOT(b,0,ih) \
                + (size_t)(wmr*64 + ii*16 + cn)*64 + ((kk*4 + quad) ^ e8)*8); \
        _Pragma("unroll") \
        for (int jj = 0; jj < 2; ++jj) \
            bfv[jj][kk] = *(const bf16x8*)(SLOT(b,1,jh) \
                + (size_t)(wnr*32 + jj*16 + cn)*64 + ((kk*4 + quad) ^ e8)*8); \
    } \
    STG; \
    WT; \
    __builtin_amdgcn_s_barrier(); \
    __builtin_amdgcn_s_setprio(1); \
    /* MFMA kk-outer: first 8 need only the kk0 batch (compiler emits */ \
    /* counted lgkmcnt(6)); kk1 batch drains underneath. */ \
    _Pragma("unroll") \
    for (int kk = 0; kk < 2; ++kk) \
        _Pragma("unroll") \
        for (int ii = 0; ii < 4; ++ii) \
            _Pragma("unroll") \
            for (int jj = 0; jj < 2; ++jj) \
                acc[(ih)*4 + ii][(jh)*2 + jj] = \
                    __builtin_amdgcn_mfma_f32_16x16x32_bf16( \
                        af[ii][kk], bfv[jj][kk], \
                        acc[(ih)*4 + ii][(jh)*2 + jj], 0, 0, 0); \
    __builtin_amdgcn_s_setprio(0); \
    __builtin_amdgcn_s_barrier(); \
} while(0)

    // prologue: tile0 (all 4 halves) + tile1 {A0, B1}
    STAGE(0,0,0, 0, Ag); STAGE(0,1,0, 0, Bg);
    STAGE(0,0,1, 0, Ag); STAGE(0,1,1, 0, Bg);
    STAGE(1,0,0, 1, Ag); STAGE(1,1,1, 1, Bg);
    asm volatile("s_waitcnt vmcnt(4)" ::: "memory");
    __builtin_amdgcn_s_barrier();

    #pragma unroll 1
    for (int it = 0; it < 8; ++it) {
        const int t1 = 2*it + 1, t2 = 2*it + 2, t3 = 2*it + 3;
        const bool pf = (it < 7);
        PHASE(0, 0, 0, { STAGE(1,0,1, t1, Ag); }, {});
        PHASE(0, 0, 1, { STAGE(1,1,0, t1, Bg); }, {});
        PHASE(0, 1, 1, { if (pf) STAGE(0,0,0, t2, Ag); }, {});
        PHASE(0, 1, 0, { if (pf) STAGE(0,1,1, t2, Bg); },
              { if (pf) asm volatile("s_waitcnt vmcnt(4)" ::: "memory");
                else    asm volatile("s_waitcnt vmcnt(0)" ::: "memory"); });
        PHASE(1, 0, 0, { if (pf) STAGE(0,0,1, t2, Ag); }, {});
        PHASE(1, 0, 1, { if (pf) STAGE(0,1,0, t2, Bg); }, {});
        PHASE(1, 1, 1, { if (pf) STAGE(1,0,0, t3, Ag); }, {});
        PHASE(1, 1, 0, { if (pf) STAGE(1,1,1, t3, Bg); },
              { if (pf) asm volatile("s_waitcnt vmcnt(4)" ::: "memory");
                else    asm volatile("s_waitcnt vmcnt(0)" ::: "memory"); });
    }
#undef PHASE
#undef STAGE
#undef SLOT

    // epilogue — (s, mat) are block-uniform (768 = 3*256, col0 % 256 == 0)
    const int s    = col0 / 768;
    const int rem  = col0 - s*768;
    const int mat  = rem >> 8;                 // 0:g1  1:dre  2:dim
    const float* bias = (mat == 0) ? bg1 : ((mat == 1) ? bdr : bdi);

    int dloc[4]; float bv[4];
    #pragma unroll
    for (int j = 0; j < 4; ++j) {
        dloc[j] = (j >> 1)*128 + wnr*32 + (j & 1)*16 + cn;
        bv[j] = bias[s*D_ + dloc[j]];
    }

    #pragma unroll
    for (int i = 0; i < 8; ++i) {
        const int m = row0 + (i >> 2)*128 + wmr*64 + (i & 3)*16 + quad*4;
        #pragma unroll
        for (int j = 0; j < 4; ++j) {
            const int d = dloc[j];
            const f32x4 v = acc[i][j];
            if (mat == 0) {
                unsigned short* gp = g1b + ((size_t)s*BT_ + m)*D_ + d;
                #pragma unroll
                for (int r = 0; r < 4; ++r)
                    gp[(size_t)r*D_] = f2bf(fmaxf(v[r] + bv[j], 0.f));
            } else {
                const size_t base = (size_t)m*(S_*2*D_) + s*2*D_
                                  + (mat == 2 ? D_ : 0) + d;
                if (DRVB) {
                    #pragma unroll
                    for (int r = 0; r < 4; ++r)
                        drvb[base + (size_t)r*(S_*2*D_)] = f2bf(v[r] + bv[j]);
                } else {
                    #pragma unroll
                    for (int r = 0; r < 4; ++r)
                        drvf[base + (size_t)r*(S_*2*D_)] = v[r] + bv[j];
                }
            }
        }
    }
}

// ---------------------------------------------------------------------------
// k2: per-s  omg = sigmoid(-(g1 @ Wg2 + bg2)) -> u16 fixed-point
// ---------------------------------------------------------------------------
__global__ __launch_bounds__(256) void k2_mfma(
    const unsigned short* __restrict__ g1b,
    const unsigned short* __restrict__ B2t,
    const float* __restrict__ bg2, unsigned short* __restrict__ omgu)
{
    __shared__ unsigned short As[128*64];
    __shared__ unsigned short Bs[128*64];

    const int tid = threadIdx.x;
    const int wave = tid >> 6, lane = tid & 63;
    const int wm = (wave >> 1) * 64, wn = (wave & 1) * 64;
    const int row0 = blockIdx.x * 128, col0 = blockIdx.y * 128;
    const int s = blockIdx.z;

    const f32x4 z = {0.f, 0.f, 0.f, 0.f};
    f32x4 acc[4][4];
    #pragma unroll
    for (int i = 0; i < 4; ++i)
        #pragma unroll
        for (int j = 0; j < 4; ++j) acc[i][j] = z;

    const unsigned short* Ag = g1b + ((size_t)s*BT_ + row0)*D_;
    const unsigned short* Bg = B2t + (size_t)s*D_*D_ + (size_t)col0*D_;
    const int lrow = lane >> 3;
    const int lksw = ((lane & 7) ^ lrow) * 8;
    const int cn   = lane & 15, quad = lane >> 4;
    const int e    = cn & 7;

    for (int k0 = 0; k0 < D_; k0 += 64) {
        #pragma unroll
        for (int t = 0; t < 4; ++t) {
            const int m0 = wave*32 + t*8;
            GLD_LDS(Ag + (size_t)(m0 + lrow)*D_ + k0 + lksw, As + m0*64);
            GLD_LDS(Bg + (size_t)(m0 + lrow)*D_ + k0 + lksw, Bs + m0*64);
        }
        __syncthreads();
        #pragma unroll
        for (int ks = 0; ks < 2; ++ks) {
            const int offs = (((ks*4 + quad) ^ e)) * 8;
            bf16x8 af[4], bfv[4];
            #pragma unroll
            for (int i = 0; i < 4; ++i)
                af[i] = *(const bf16x8*)(As + (wm + i*16 + cn)*64 + offs);
            #pragma unroll
            for (int j = 0; j < 4; ++j)
                bfv[j] = *(const bf16x8*)(Bs + (wn + j*16 + cn)*64 + offs);
            #pragma unroll
            for (int i = 0; i < 4; ++i)
                #pragma unroll
                for (int j = 0; j < 4; ++j)
                    acc[i][j] = __builtin_amdgcn_mfma_f32_16x16x32_bf16(
                        af[i], bfv[j], acc[i][j], 0, 0, 0);
        }
        __syncthreads();
    }

    const int qr = quad * 4;
    float bv[4];
    #pragma unroll
    for (int j = 0; j < 4; ++j) bv[j] = bg2[s*D_ + col0 + wn + j*16 + cn];

    #pragma unroll
    for (int i = 0; i < 4; ++i) {
        const int m = row0 + wm + i*16 + qr;
        #pragma unroll
        for (int j = 0; j < 4; ++j) {
            const int d = col0 + wn + j*16 + cn;
            const f32x4 v = acc[i][j];
            unsigned short* op = omgu + ((size_t)s*BT_ + m)*D_ + d;
            #pragma unroll
            for (int r = 0; r < 4; ++r) {
                const float om = 1.f / (1.f + __expf(v[r] + bv[j]));
                op[(size_t)r*D_] =
                    (unsigned short)fminf(om * 65536.f, 65535.f);
            }
        }
    }
}

// ---------------------------------------------------------------------------
// k3a: per-chunk summaries. 128 threads, 2 channels each, packed loads.
// ---------------------------------------------------------------------------
template<bool DRVB>
__global__ __launch_bounds__(128) void k3a_chunk(
    const unsigned short* __restrict__ omgu,
    const unsigned short* __restrict__ drvb, const float* __restrict__ drvf,
    float4* __restrict__ summ, SC sc)
{
    const int blk = blockIdx.x;
    const int c = blk & (CHUNKS-1);
    const int s = (blk >> 7) & (S_-1);
    const int b = blk >> 9;
    const int d2 = threadIdx.x;     // channels 2*d2, 2*d2+1

    const float are = sc.are[s], aim = sc.aim[s], bs = sc.bsc[s];
    float Ar[2] = {1.f,1.f}, Ai[2] = {0,0}, Hr[2] = {0,0}, Hi[2] = {0,0};
    const int t0 = c * CL;

    #pragma unroll 4
    for (int t = 0; t < CL; ++t) {
        const int bt = b*T_ + t0 + t;
        const unsigned int ov =
            *(const unsigned int*)(omgu + ((size_t)s*BT_ + bt)*D_ + 2*d2);
        const float om[2] = { u16om(ov & 0xFFFFu), u16om(ov >> 16) };
        const size_t base = (size_t)bt*(S_*2*D_) + s*2*D_ + 2*d2;
        float dre[2], dim[2];
        if (DRVB) {
            const unsigned int ur = *(const unsigned int*)(drvb + base);
            const unsigned int ui = *(const unsigned int*)(drvb + base + D_);
            dre[0] = bf2f_lo(ur); dre[1] = bf2f_hi(ur);
            dim[0] = bf2f_lo(ui); dim[1] = bf2f_hi(ui);
        } else {
            const float2 fr = *(const float2*)(drvf + base);
            const float2 fi = *(const float2*)(drvf + base + D_);
            dre[0] = fr.x; dre[1] = fr.y; dim[0] = fi.x; dim[1] = fi.y;
        }
        #pragma unroll
        for (int u = 0; u < 2; ++u) {
            const float ar = om[u]*are, ai = om[u]*aim, ob = om[u]*bs;
            const float br = ob*dre[u], bi = ob*dim[u];
            const float nHr = ar*Hr[u] - ai*Hi[u] + br;
            const float nHi = ar*Hi[u] + ai*Hr[u] + bi;
            const float nAr = ar*Ar[u] - ai*Ai[u];
            const float nAi = ar*Ai[u] + ai*Ar[u];
            Hr[u]=nHr; Hi[u]=nHi; Ar[u]=nAr; Ai[u]=nAi;
        }
    }
    const size_t so = ((size_t)(b*S_ + s)*CHUNKS + c)*D_ + 2*d2;
    summ[so]     = make_float4(Ar[0], Ai[0], Hr[0], Hi[0]);
    summ[so + 1] = make_float4(Ar[1], Ai[1], Hr[1], Hi[1]);
}

// ---------------------------------------------------------------------------
// k3b: parallel segmented scan over the 128 chunk summaries per channel.
// ---------------------------------------------------------------------------
__global__ __launch_bounds__(256) void k3b_scan(float4* __restrict__ summ)
{
    __shared__ float4 sb[2][CHUNKS];
    const int ch = threadIdx.x >> 7;
    const int c  = threadIdx.x & (CHUNKS-1);
    const int channel = blockIdx.x*2 + ch;
    const int d = channel & (D_-1);
    const int s = (channel >> 8) & (S_-1);
    const int b = channel >> 10;
    const size_t off = ((size_t)(b*S_ + s)*CHUNKS + c)*D_ + d;

    float4 v = summ[off];
    sb[ch][c] = v;
    __syncthreads();
    #pragma unroll
    for (int st = 1; st < CHUNKS; st <<= 1) {
        float4 l;
        if (c >= st) l = sb[ch][c - st];
        __syncthreads();
        if (c >= st) {
            float4 nv;
            nv.x = l.x*v.x - l.y*v.y;
            nv.y = l.x*v.y + l.y*v.x;
            nv.z = v.x*l.z - v.y*l.w + v.z;
            nv.w = v.x*l.w + v.y*l.z + v.w;
            v = nv;
            sb[ch][c] = v;
        }
        __syncthreads();
    }
    float2 carry = make_float2(0.f, 0.f);
    if (c > 0) { const float4 p = sb[ch][c-1]; carry = make_float2(p.z, p.w); }
    *(float2*)&summ[off] = carry;
}

// ---------------------------------------------------------------------------
// k3c: final pass — redo local scan with carry, write h (fp32) to out.
// ---------------------------------------------------------------------------
template<bool DRVB>
__global__ __launch_bounds__(128) void k3c_final(
    const unsigned short* __restrict__ omgu,
    const unsigned short* __restrict__ drvb, const float* __restrict__ drvf,
    float* __restrict__ out, const float4* __restrict__ summ, SC sc)
{
    const int blk = blockIdx.x;
    const int c = blk & (CHUNKS-1);
    const int s = (blk >> 7) & (S_-1);
    const int b = blk >> 9;
    const int d2 = threadIdx.x;

    const float are = sc.are[s], aim = sc.aim[s], bs = sc.bsc[s];
    const size_t so = ((size_t)(b*S_ + s)*CHUNKS + c)*D_ + 2*d2;
    const float4 v0 = summ[so];
    const float4 v1 = summ[so + 1];
    float Hr[2] = {v0.x, v1.x}, Hi[2] = {v0.y, v1.y};
    const int t0 = c * CL;

    #pragma unroll 4
    for (int t = 0; t < CL; ++t) {
        const int bt = b*T_ + t0 + t;
        const unsigned int ov =
            *(const unsigned int*)(omgu + ((size_t)s*BT_ + bt)*D_ + 2*d2);
        const float om[2] = { u16om(ov & 0xFFFFu), u16om(ov >> 16) };
        const size_t base = (size_t)bt*(S_*2*D_) + s*2*D_ + 2*d2;
        float dre[2], dim[2];
        if (DRVB) {
            const unsigned int ur = *(const unsigned int*)(drvb + base);
            const unsigned int ui = *(const unsigned int*)(drvb + base + D_);
            dre[0] = bf2f_lo(ur); dre[1] = bf2f_hi(ur);
            dim[0] = bf2f_lo(ui); dim[1] = bf2f_hi(ui);
        } else {
            const float2 fr = *(const float2*)(drvf + base);
            const float2 fi = *(const float2*)(drvf + base + D_);
            dre[0] = fr.x; dre[1] = fr.y; dim[0] = fi.x; dim[1] = fi.y;
        }
        #pragma unroll
        for (int u = 0; u < 2; ++u) {
            const float ar = om[u]*are, ai = om[u]*aim, ob = om[u]*bs;
            const float br = ob*dre[u], bi = ob*dim[u];
            const float nHr = ar*Hr[u] - ai*Hi[u] + br;
            const float nHi = ar*Hi[u] + ai*Hr[u] + bi;
            Hr[u]=nHr; Hi[u]=nHi;
        }
        *(float2*)(out + base)      = make_float2(Hr[0], Hr[1]);
        *(float2*)(out + base + D_) = make_float2(Hi[0], Hi[1]);
    }
}

// ---------------------------------------------------------------------------
extern "C" void kernel_launch(void* const* d_in, const int* in_sizes, int n_in,
                              void* d_out, int out_size, void* d_ws, size_t ws_size,
                              hipStream_t stream)
{
    const float* x   = (const float*)d_in[0];
    const float* Wg1 = (const float*)d_in[1];
    const float* bg1 = (const float*)d_in[2];
    const float* Wg2 = (const float*)d_in[3];
    const float* bg2 = (const float*)d_in[4];
    const float* Wdr = (const float*)d_in[5];
    const float* bdr = (const float*)d_in[6];
    const float* Wdi = (const float*)d_in[7];
    const float* bdi = (const float*)d_in[8];
    float* out = (float*)d_out;

    // workspace layout (141.0 MB total):
    //   [0, 33.5M)      g1b (k1..k2)  -> summ (k3a..k3c)       alias OK
    //   [33.5M, 34.1M)  B2t (conv..k2)
    //   [34.1M, 67.6M)  xb  (conv..k1) -> omgu (k2..k3c)       alias OK
    //   [67.6M, 73.9M)  Bct (conv..k1)
    //   [73.9M, 141.0M) drvb bf16 (k1..k3c)   [if ws fits, else fp32 in out]
    char* ws = (char*)d_ws;
    unsigned short* g1b  = (unsigned short*)(ws + 0);
    float4*         summ = (float4*)(ws + 0);
    unsigned short* B2t  = (unsigned short*)(ws + 33554432);
    unsigned short* xb   = (unsigned short*)(ws + 34078720);
    unsigned short* omgu = (unsigned short*)(ws + 34078720);
    unsigned short* Bct  = (unsigned short*)(ws + 67633152);
    unsigned short* drvb = (unsigned short*)(ws + 73924608);
    const bool drv_bf16 = ws_size >= (size_t)73924608 + 67108864;

    SC sc;
    {
        const double r[S_]  = {1.0, 0.999, 0.9495, 0.9};
        const double th[S_] = {0.0, 0.01, 0.505, 1.0};
        for (int s = 0; s < S_; ++s) {
            sc.are[s] = (float)(r[s] * cos(th[s]));
            sc.aim[s] = (float)(r[s] * sin(th[s]));
            sc.bsc[s] = (r[s] >= 1.0) ? (float)(1.0/16.0) : (float)(1.0 - r[s]);
        }
    }

    // conversions
    kconv_x<<<(BT_*DIN)/1024, 256, 0, stream>>>(x, xb);
    kconv_w3<<<dim3(32,8,12), 256, 0, stream>>>(Wg1, Wdr, Wdi, Bct);
    kconv_w<<<dim3(8,8,S_),  256, 0, stream>>>(Wg2, B2t, D_, D_, (size_t)D_*D_);

    // GEMMs
    if (drv_bf16)
        k1_8p<true><<<dim3(BT_/256, GN/256), 512, 0, stream>>>(
            xb, Bct, bg1, bdr, bdi, g1b, drvb, out);
    else
        k1_8p<false><<<dim3(BT_/256, GN/256), 512, 0, stream>>>(
            xb, Bct, bg1, bdr, bdi, g1b, drvb, out);
    k2_mfma<<<dim3(BT_/128, D_/128, S_), 256, 0, stream>>>(g1b, B2t, bg2, omgu);

    // scan
    if (drv_bf16) {
        k3a_chunk<true><<<B_*S_*CHUNKS, 128, 0, stream>>>(omgu, drvb, out, summ, sc);
        k3b_scan       <<<(B_*S_*D_)/2, 256, 0, stream>>>(summ);
        k3c_final<true><<<B_*S_*CHUNKS, 128, 0, stream>>>(omgu, drvb, out, out, summ, sc);
    } else {
        k3a_chunk<false><<<B_*S_*CHUNKS, 128, 0, stream>>>(omgu, drvb, out, summ, sc);
        k3b_scan        <<<(B_*S_*D_)/2, 256, 0, stream>>>(summ);
        k3c_final<false><<<B_*S_*CHUNKS, 128, 0, stream>>>(omgu, drvb, out, out, summ, sc);
    }
}

// Round 5
// 411.218 us; speedup vs baseline: 1.0083x; 1.0083x over previous
//
#include <hip/hip_runtime.h>
#include <cmath>

#define S_   4
#define DIN  1024
#define D_   256
#define B_   4
#define T_   4096
#define BT_  (B_*T_)
#define GN   (S_*3*D_)     // 3072 concat N for the big GEMM
#define CHUNKS 128
#define CL   (T_/CHUNKS)   // 32

typedef short bf16x8 __attribute__((ext_vector_type(8)));
typedef float f32x4  __attribute__((ext_vector_type(4)));

struct SC { float are[S_]; float aim[S_]; float bsc[S_]; };

__device__ inline unsigned short f2bf(float f) {
    unsigned int u = __builtin_bit_cast(unsigned int, f);
    unsigned int r = (u + 0x7FFFu + ((u >> 16) & 1u)) >> 16;
    return (unsigned short)r;
}
__device__ inline float bf2f_lo(unsigned int u) {
    return __builtin_bit_cast(float, u << 16);
}
__device__ inline float bf2f_hi(unsigned int u) {
    return __builtin_bit_cast(float, u & 0xFFFF0000u);
}
// omg u16 fixed-point decode: (u + 0.5) / 65536
__device__ inline float u16om(unsigned int u) {
    return ((float)u + 0.5f) * (1.f/65536.f);
}

#define GLD_LDS(gp, lp) \
    __builtin_amdgcn_global_load_lds( \
        (const __attribute__((address_space(1))) void*)(gp), \
        (__attribute__((address_space(3))) void*)(lp), 16, 0, 0)

// ---------------------------------------------------------------------------
// kconv_all: merged conversion kernel (saves 2 launches).
//   blocks [0, 16384)          : x fp32 -> bf16
//   blocks [16384, 19456)      : Wg1/Wdr/Wdi transpose -> Bct  (32x8x12)
//   blocks [19456, 19712)      : Wg2 transpose -> B2t          (8x8x4)
// ---------------------------------------------------------------------------
__global__ __launch_bounds__(256) void kconv_all(
    const float* __restrict__ x,
    const float* __restrict__ Wg1, const float* __restrict__ Wdr,
    const float* __restrict__ Wdi, const float* __restrict__ Wg2,
    unsigned short* __restrict__ xb, unsigned short* __restrict__ Bct,
    unsigned short* __restrict__ B2t)
{
    const int bid = blockIdx.x;
    if (bid < 16384) {
        const size_t i = ((size_t)bid*256 + threadIdx.x)*4;
        const float4 v = *(const float4*)(x + i);
        ushort4 o;
        o.x = f2bf(v.x); o.y = f2bf(v.y); o.z = f2bf(v.z); o.w = f2bf(v.w);
        *(ushort4*)(xb + i) = o;
        return;
    }
    __shared__ float t[32][33];
    const int c = threadIdx.x & 31, r0 = threadIdx.x >> 5;
    if (bid < 19456) {
        const int tt = bid - 16384;
        const int kb = tt & 31, nb = (tt >> 5) & 7, z = tt >> 8;
        const int widx = z >> 2, s = z & 3;
        const float* src = (widx == 0) ? Wg1 : ((widx == 1) ? Wdr : Wdi);
        const float* sp = src + (size_t)s*DIN*D_;
        unsigned short* dp = Bct + (size_t)s*768*DIN + (size_t)widx*D_*DIN;
        const int k0 = kb*32, n0 = nb*32;
        #pragma unroll
        for (int p = 0; p < 4; ++p)
            t[r0 + p*8][c] = sp[(size_t)(k0 + r0 + p*8)*D_ + n0 + c];
        __syncthreads();
        #pragma unroll
        for (int p = 0; p < 4; ++p)
            dp[(size_t)(n0 + r0 + p*8)*DIN + k0 + c] = f2bf(t[c][r0 + p*8]);
    } else {
        const int tt = bid - 19456;
        const int kb = tt & 7, nb = (tt >> 3) & 7, s = tt >> 6;
        const float* sp = Wg2 + (size_t)s*D_*D_;
        unsigned short* dp = B2t + (size_t)s*D_*D_;
        const int k0 = kb*32, n0 = nb*32;
        #pragma unroll
        for (int p = 0; p < 4; ++p)
            t[r0 + p*8][c] = sp[(size_t)(k0 + r0 + p*8)*D_ + n0 + c];
        __syncthreads();
        #pragma unroll
        for (int p = 0; p < 4; ++p)
            dp[(size_t)(n0 + r0 + p*8)*D_ + k0 + c] = f2bf(t[c][r0 + p*8]);
    }
}

// ---------------------------------------------------------------------------
// k1_8p: C[16384][3072] = xb * Bct^T, 256x256 tile, BK=64, 8 waves (2M x 4N),
// 8-phase schedule, counted vmcnt, st-swizzled LDS (R1 PHASE — best measured).
// R5: k2 FUSED into the mat0 epilogue. A mat0 block holds the complete K=256
// of one scale's g1, so after the main loop: g1 (bias+relu, bf16) -> L
// (swizzled, 4 k-slices of [256 rows][64 k]); GEMM2 vs B2t staged in Bs2
// (32 KiB, single-buffered, 4 K-tiles); sigmoid -> omgu u16. LDS = 160 KiB.
// ---------------------------------------------------------------------------
template<bool DRVB>
__global__ __launch_bounds__(512, 2) void k1_8p(
    const unsigned short* __restrict__ xb,
    const unsigned short* __restrict__ Bct,
    const unsigned short* __restrict__ B2t,
    const float* __restrict__ bg1, const float* __restrict__ bg2,
    const float* __restrict__ bdr, const float* __restrict__ bdi,
    unsigned short* __restrict__ omgu,
    unsigned short* __restrict__ drvb, float* __restrict__ drvf)
{
    __shared__ unsigned short L[8*8192];    // 128 KiB
    __shared__ unsigned short Bs2[16384];   // 32 KiB (GEMM2 B staging)

    const int tid  = threadIdx.x;
    const int wave = tid >> 6, lane = tid & 63;
    const int wmr  = wave >> 2;            // 0..1  (64-row group within a half)
    const int wnr  = wave & 3;             // 0..3  (32-col group within a half)
    const int row0 = blockIdx.x * 256, col0 = blockIdx.y * 256;
    const int cn = lane & 15, quad = lane >> 4;
    const int e8 = cn & 7;
    const int srow = lane >> 3;                    // staging row-in-8
    const int lksw = ((lane & 7) ^ srow) * 8;      // pre-swizzled src k offset

    const unsigned short* Ag = xb  + (size_t)row0 * DIN;
    const unsigned short* Bg = Bct + (size_t)col0 * DIN;

    f32x4 acc[8][4];
    const f32x4 z = {0.f, 0.f, 0.f, 0.f};
    #pragma unroll
    for (int i = 0; i < 8; ++i)
        #pragma unroll
        for (int j = 0; j < 4; ++j) acc[i][j] = z;

#define SLOT(b,o,h) (L + (((b)*4 + (o)*2 + (h)) * 8192))
// stage one 128x64 half-tile (2 x global_load_lds per thread-wave)
#define STAGE(b,o,h,kt,Gp) do { \
    const unsigned short* _g = (Gp) + (size_t)((h)*128 + wave*8 + srow)*DIN \
                             + (size_t)(kt)*64 + lksw; \
    unsigned short* _l = SLOT(b,o,h) + wave*512; \
    GLD_LDS(_g, _l); \
    GLD_LDS(_g + (size_t)64*DIN, _l + 4096); \
} while(0)

#define PHASE(b, ih, jh, STG, WT) do { \
    bf16x8 af[4][2], bfv[2][2]; \
    _Pragma("unroll") \
    for (int ii = 0; ii < 4; ++ii) { \
        const unsigned short* ap = SLOT(b,0,ih) + (size_t)(wmr*64 + ii*16 + cn)*64; \
        _Pragma("unroll") \
        for (int kk = 0; kk < 2; ++kk) \
            af[ii][kk] = *(const bf16x8*)(ap + ((kk*4 + quad) ^ e8)*8); \
    } \
    _Pragma("unroll") \
    for (int jj = 0; jj < 2; ++jj) { \
        const unsigned short* bp = SLOT(b,1,jh) + (size_t)(wnr*32 + jj*16 + cn)*64; \
        _Pragma("unroll") \
        for (int kk = 0; kk < 2; ++kk) \
            bfv[jj][kk] = *(const bf16x8*)(bp + ((kk*4 + quad) ^ e8)*8); \
    } \
    STG; \
    WT; \
    __builtin_amdgcn_s_barrier(); \
    asm volatile("s_waitcnt lgkmcnt(0)" ::: "memory"); \
    __builtin_amdgcn_s_setprio(1); \
    _Pragma("unroll") \
    for (int ii = 0; ii < 4; ++ii) \
        _Pragma("unroll") \
        for (int jj = 0; jj < 2; ++jj) \
            _Pragma("unroll") \
            for (int kk = 0; kk < 2; ++kk) \
                acc[(ih)*4 + ii][(jh)*2 + jj] = \
                    __builtin_amdgcn_mfma_f32_16x16x32_bf16( \
                        af[ii][kk], bfv[jj][kk], \
                        acc[(ih)*4 + ii][(jh)*2 + jj], 0, 0, 0); \
    __builtin_amdgcn_s_setprio(0); \
    __builtin_amdgcn_s_barrier(); \
} while(0)

    // prologue: tile0 (all 4 halves) + tile1 {A0, B1}
    STAGE(0,0,0, 0, Ag); STAGE(0,1,0, 0, Bg);
    STAGE(0,0,1, 0, Ag); STAGE(0,1,1, 0, Bg);
    STAGE(1,0,0, 1, Ag); STAGE(1,1,1, 1, Bg);
    asm volatile("s_waitcnt vmcnt(4)" ::: "memory");
    __builtin_amdgcn_s_barrier();

    #pragma unroll 1
    for (int it = 0; it < 8; ++it) {
        const int t1 = 2*it + 1, t2 = 2*it + 2, t3 = 2*it + 3;
        const bool pf = (it < 7);
        PHASE(0, 0, 0, { STAGE(1,0,1, t1, Ag); }, {});
        PHASE(0, 0, 1, { STAGE(1,1,0, t1, Bg); }, {});
        PHASE(0, 1, 1, { if (pf) STAGE(0,0,0, t2, Ag); }, {});
        PHASE(0, 1, 0, { if (pf) STAGE(0,1,1, t2, Bg); },
              { if (pf) asm volatile("s_waitcnt vmcnt(4)" ::: "memory");
                else    asm volatile("s_waitcnt vmcnt(0)" ::: "memory"); });
        PHASE(1, 0, 0, { if (pf) STAGE(0,0,1, t2, Ag); }, {});
        PHASE(1, 0, 1, { if (pf) STAGE(0,1,0, t2, Bg); }, {});
        PHASE(1, 1, 1, { if (pf) STAGE(1,0,0, t3, Ag); }, {});
        PHASE(1, 1, 0, { if (pf) STAGE(1,1,1, t3, Bg); },
              { if (pf) asm volatile("s_waitcnt vmcnt(4)" ::: "memory");
                else    asm volatile("s_waitcnt vmcnt(0)" ::: "memory"); });
    }
#undef PHASE
#undef STAGE
#undef SLOT

    // epilogue — (s, mat) are block-uniform (768 = 3*256, col0 % 256 == 0)
    const int s    = col0 / 768;
    const int rem  = col0 - s*768;
    const int mat  = rem >> 8;                 // 0:g1(fused gate)  1:dre  2:dim

    if (mat == 0) {
        // ---- fused gate path: g1 -> LDS (bf16, swizzled), GEMM2, sigmoid ----
        int dloc[4]; float bv[4];
        #pragma unroll
        for (int j = 0; j < 4; ++j) {
            dloc[j] = (j >> 1)*128 + wnr*32 + (j & 1)*16 + cn;
            bv[j] = bg1[s*D_ + dloc[j]];
        }
        __syncthreads();
        // store g1: slice (c>>6) of [256 rows][64 k], elem addr =
        //   slice*16384 + row*64 + ((cc>>3) ^ (row&7))*8 + (cc&7)
        #pragma unroll
        for (int i = 0; i < 8; ++i) {
            const int rowb = (i >> 2)*128 + wmr*64 + (i & 3)*16 + quad*4;
            #pragma unroll
            for (int j = 0; j < 4; ++j) {
                const int c = dloc[j];
                const int sl = (c >> 6)*16384, cc = c & 63, c7 = c & 7;
                #pragma unroll
                for (int r = 0; r < 4; ++r) {
                    const int row = rowb + r;
                    L[sl + row*64 + (((cc >> 3) ^ (row & 7))*8) + c7] =
                        f2bf(fmaxf(acc[i][j][r] + bv[j], 0.f));
                }
            }
        }
        __syncthreads();

        // GEMM2: omg_pre[256][256] = g1 @ Wg2 (B2t is [e][k])
        const unsigned short* B2p = B2t + (size_t)s*D_*D_;
        f32x4 acc2[8][4];
        #pragma unroll
        for (int i = 0; i < 8; ++i)
            #pragma unroll
            for (int j = 0; j < 4; ++j) acc2[i][j] = z;

        #pragma unroll 1
        for (int kt = 0; kt < 4; ++kt) {
            #pragma unroll
            for (int ld = 0; ld < 4; ++ld)
                GLD_LDS(B2p + (size_t)(ld*64 + wave*8 + srow)*D_ + kt*64 + lksw,
                        Bs2 + (ld*64 + wave*8)*64);
            asm volatile("s_waitcnt vmcnt(0)" ::: "memory");
            __syncthreads();
            bf16x8 b2[4][2];
            #pragma unroll
            for (int jj = 0; jj < 4; ++jj)
                #pragma unroll
                for (int kk = 0; kk < 2; ++kk)
                    b2[jj][kk] = *(const bf16x8*)(Bs2
                        + (size_t)(wnr*64 + jj*16 + cn)*64
                        + ((kk*4 + quad) ^ e8)*8);
            #pragma unroll
            for (int ii = 0; ii < 8; ++ii) {
                bf16x8 a2[2];
                #pragma unroll
                for (int kk = 0; kk < 2; ++kk)
                    a2[kk] = *(const bf16x8*)(L + kt*16384
                        + (size_t)(wmr*128 + ii*16 + cn)*64
                        + ((kk*4 + quad) ^ e8)*8);
                #pragma unroll
                for (int kk = 0; kk < 2; ++kk)
                    #pragma unroll
                    for (int jj = 0; jj < 4; ++jj)
                        acc2[ii][jj] = __builtin_amdgcn_mfma_f32_16x16x32_bf16(
                            a2[kk], b2[jj][kk], acc2[ii][jj], 0, 0, 0);
            }
            __syncthreads();
        }

        // sigmoid epilogue: omg = 1/(1+exp(z+bg2)) -> u16
        float bv2[4];
        #pragma unroll
        for (int jj = 0; jj < 4; ++jj)
            bv2[jj] = bg2[s*D_ + wnr*64 + jj*16 + cn];
        #pragma unroll
        for (int ii = 0; ii < 8; ++ii) {
            const int m = row0 + wmr*128 + ii*16 + quad*4;
            #pragma unroll
            for (int jj = 0; jj < 4; ++jj) {
                const int d = wnr*64 + jj*16 + cn;
                unsigned short* op = omgu + ((size_t)s*BT_ + m)*D_ + d;
                #pragma unroll
                for (int r = 0; r < 4; ++r) {
                    const float om = 1.f / (1.f + __expf(acc2[ii][jj][r] + bv2[jj]));
                    op[(size_t)r*D_] =
                        (unsigned short)fminf(om * 65536.f, 65535.f);
                }
            }
        }
    } else {
        // ---- drive path (unchanged) ----
        const float* bias = (mat == 1) ? bdr : bdi;
        int dloc[4]; float bv[4];
        #pragma unroll
        for (int j = 0; j < 4; ++j) {
            dloc[j] = (j >> 1)*128 + wnr*32 + (j & 1)*16 + cn;
            bv[j] = bias[s*D_ + dloc[j]];
        }
        #pragma unroll
        for (int i = 0; i < 8; ++i) {
            const int m = row0 + (i >> 2)*128 + wmr*64 + (i & 3)*16 + quad*4;
            #pragma unroll
            for (int j = 0; j < 4; ++j) {
                const int d = dloc[j];
                const f32x4 v = acc[i][j];
                const size_t base = (size_t)m*(S_*2*D_) + s*2*D_
                                  + (mat == 2 ? D_ : 0) + d;
                if (DRVB) {
                    #pragma unroll
                    for (int r = 0; r < 4; ++r)
                        drvb[base + (size_t)r*(S_*2*D_)] = f2bf(v[r] + bv[j]);
                } else {
                    #pragma unroll
                    for (int r = 0; r < 4; ++r)
                        drvf[base + (size_t)r*(S_*2*D_)] = v[r] + bv[j];
                }
            }
        }
    }
}

// ---------------------------------------------------------------------------
// k3a: per-chunk summaries. 128 threads, 2 channels each, packed loads.
// ---------------------------------------------------------------------------
template<bool DRVB>
__global__ __launch_bounds__(128) void k3a_chunk(
    const unsigned short* __restrict__ omgu,
    const unsigned short* __restrict__ drvb, const float* __restrict__ drvf,
    float4* __restrict__ summ, SC sc)
{
    const int blk = blockIdx.x;
    const int c = blk & (CHUNKS-1);
    const int s = (blk >> 7) & (S_-1);
    const int b = blk >> 9;
    const int d2 = threadIdx.x;     // channels 2*d2, 2*d2+1

    const float are = sc.are[s], aim = sc.aim[s], bs = sc.bsc[s];
    float Ar[2] = {1.f,1.f}, Ai[2] = {0,0}, Hr[2] = {0,0}, Hi[2] = {0,0};
    const int t0 = c * CL;

    #pragma unroll 4
    for (int t = 0; t < CL; ++t) {
        const int bt = b*T_ + t0 + t;
        const unsigned int ov =
            *(const unsigned int*)(omgu + ((size_t)s*BT_ + bt)*D_ + 2*d2);
        const float om[2] = { u16om(ov & 0xFFFFu), u16om(ov >> 16) };
        const size_t base = (size_t)bt*(S_*2*D_) + s*2*D_ + 2*d2;
        float dre[2], dim[2];
        if (DRVB) {
            const unsigned int ur = *(const unsigned int*)(drvb + base);
            const unsigned int ui = *(const unsigned int*)(drvb + base + D_);
            dre[0] = bf2f_lo(ur); dre[1] = bf2f_hi(ur);
            dim[0] = bf2f_lo(ui); dim[1] = bf2f_hi(ui);
        } else {
            const float2 fr = *(const float2*)(drvf + base);
            const float2 fi = *(const float2*)(drvf + base + D_);
            dre[0] = fr.x; dre[1] = fr.y; dim[0] = fi.x; dim[1] = fi.y;
        }
        #pragma unroll
        for (int u = 0; u < 2; ++u) {
            const float ar = om[u]*are, ai = om[u]*aim, ob = om[u]*bs;
            const float br = ob*dre[u], bi = ob*dim[u];
            const float nHr = ar*Hr[u] - ai*Hi[u] + br;
            const float nHi = ar*Hi[u] + ai*Hr[u] + bi;
            const float nAr = ar*Ar[u] - ai*Ai[u];
            const float nAi = ar*Ai[u] + ai*Ar[u];
            Hr[u]=nHr; Hi[u]=nHi; Ar[u]=nAr; Ai[u]=nAi;
        }
    }
    const size_t so = ((size_t)(b*S_ + s)*CHUNKS + c)*D_ + 2*d2;
    summ[so]     = make_float4(Ar[0], Ai[0], Hr[0], Hi[0]);
    summ[so + 1] = make_float4(Ar[1], Ai[1], Hr[1], Hi[1]);
}

// ---------------------------------------------------------------------------
// k3b: parallel segmented scan over the 128 chunk summaries per channel.
// ---------------------------------------------------------------------------
__global__ __launch_bounds__(256) void k3b_scan(float4* __restrict__ summ)
{
    __shared__ float4 sb[2][CHUNKS];
    const int ch = threadIdx.x >> 7;
    const int c  = threadIdx.x & (CHUNKS-1);
    const int channel = blockIdx.x*2 + ch;
    const int d = channel & (D_-1);
    const int s = (channel >> 8) & (S_-1);
    const int b = channel >> 10;
    const size_t off = ((size_t)(b*S_ + s)*CHUNKS + c)*D_ + d;

    float4 v = summ[off];
    sb[ch][c] = v;
    __syncthreads();
    #pragma unroll
    for (int st = 1; st < CHUNKS; st <<= 1) {
        float4 l;
        if (c >= st) l = sb[ch][c - st];
        __syncthreads();
        if (c >= st) {
            float4 nv;
            nv.x = l.x*v.x - l.y*v.y;
            nv.y = l.x*v.y + l.y*v.x;
            nv.z = v.x*l.z - v.y*l.w + v.z;
            nv.w = v.x*l.w + v.y*l.z + v.w;
            v = nv;
            sb[ch][c] = v;
        }
        __syncthreads();
    }
    float2 carry = make_float2(0.f, 0.f);
    if (c > 0) { const float4 p = sb[ch][c-1]; carry = make_float2(p.z, p.w); }
    *(float2*)&summ[off] = carry;
}

// ---------------------------------------------------------------------------
// k3c: final pass — redo local scan with carry, write h (fp32) to out.
// ---------------------------------------------------------------------------
template<bool DRVB>
__global__ __launch_bounds__(128) void k3c_final(
    const unsigned short* __restrict__ omgu,
    const unsigned short* __restrict__ drvb, const float* __restrict__ drvf,
    float* __restrict__ out, const float4* __restrict__ summ, SC sc)
{
    const int blk = blockIdx.x;
    const int c = blk & (CHUNKS-1);
    const int s = (blk >> 7) & (S_-1);
    const int b = blk >> 9;
    const int d2 = threadIdx.x;

    const float are = sc.are[s], aim = sc.aim[s], bs = sc.bsc[s];
    const size_t so = ((size_t)(b*S_ + s)*CHUNKS + c)*D_ + 2*d2;
    const float4 v0 = summ[so];
    const float4 v1 = summ[so + 1];
    float Hr[2] = {v0.x, v1.x}, Hi[2] = {v0.y, v1.y};
    const int t0 = c * CL;

    #pragma unroll 4
    for (int t = 0; t < CL; ++t) {
        const int bt = b*T_ + t0 + t;
        const unsigned int ov =
            *(const unsigned int*)(omgu + ((size_t)s*BT_ + bt)*D_ + 2*d2);
        const float om[2] = { u16om(ov & 0xFFFFu), u16om(ov >> 16) };
        const size_t base = (size_t)bt*(S_*2*D_) + s*2*D_ + 2*d2;
        float dre[2], dim[2];
        if (DRVB) {
            const unsigned int ur = *(const unsigned int*)(drvb + base);
            const unsigned int ui = *(const unsigned int*)(drvb + base + D_);
            dre[0] = bf2f_lo(ur); dre[1] = bf2f_hi(ur);
            dim[0] = bf2f_lo(ui); dim[1] = bf2f_hi(ui);
        } else {
            const float2 fr = *(const float2*)(drvf + base);
            const float2 fi = *(const float2*)(drvf + base + D_);
            dre[0] = fr.x; dre[1] = fr.y; dim[0] = fi.x; dim[1] = fi.y;
        }
        #pragma unroll
        for (int u = 0; u < 2; ++u) {
            const float ar = om[u]*are, ai = om[u]*aim, ob = om[u]*bs;
            const float br = ob*dre[u], bi = ob*dim[u];
            const float nHr = ar*Hr[u] - ai*Hi[u] + br;
            const float nHi = ar*Hi[u] + ai*Hr[u] + bi;
            Hr[u]=nHr; Hi[u]=nHi;
        }
        *(float2*)(out + base)      = make_float2(Hr[0], Hr[1]);
        *(float2*)(out + base + D_) = make_float2(Hi[0], Hi[1]);
    }
}

// ---------------------------------------------------------------------------
extern "C" void kernel_launch(void* const* d_in, const int* in_sizes, int n_in,
                              void* d_out, int out_size, void* d_ws, size_t ws_size,
                              hipStream_t stream)
{
    const float* x   = (const float*)d_in[0];
    const float* Wg1 = (const float*)d_in[1];
    const float* bg1 = (const float*)d_in[2];
    const float* Wg2 = (const float*)d_in[3];
    const float* bg2 = (const float*)d_in[4];
    const float* Wdr = (const float*)d_in[5];
    const float* bdr = (const float*)d_in[6];
    const float* Wdi = (const float*)d_in[7];
    const float* bdi = (const float*)d_in[8];
    float* out = (float*)d_out;

    // workspace layout (141.0 MB total):
    //   [0, 33.5M)      omgu (k1..k3c)
    //   [33.5M, 34.1M)  B2t  (conv..k1)
    //   [34.1M, 67.6M)  xb   (conv..k1) -> summ (k3a..k3c)     alias OK
    //   [67.6M, 73.9M)  Bct  (conv..k1)
    //   [73.9M, 141.0M) drvb bf16 (k1..k3c)  [if ws fits, else fp32 in out]
    char* ws = (char*)d_ws;
    unsigned short* omgu = (unsigned short*)(ws + 0);
    unsigned short* B2t  = (unsigned short*)(ws + 33554432);
    unsigned short* xb   = (unsigned short*)(ws + 34078720);
    float4*         summ = (float4*)(ws + 34078720);
    unsigned short* Bct  = (unsigned short*)(ws + 67633152);
    unsigned short* drvb = (unsigned short*)(ws + 73924608);
    const bool drv_bf16 = ws_size >= (size_t)73924608 + 67108864;

    SC sc;
    {
        const double r[S_]  = {1.0, 0.999, 0.9495, 0.9};
        const double th[S_] = {0.0, 0.01, 0.505, 1.0};
        for (int s = 0; s < S_; ++s) {
            sc.are[s] = (float)(r[s] * cos(th[s]));
            sc.aim[s] = (float)(r[s] * sin(th[s]));
            sc.bsc[s] = (r[s] >= 1.0) ? (float)(1.0/16.0) : (float)(1.0 - r[s]);
        }
    }

    // conversions (merged: x + Wg1/Wdr/Wdi + Wg2)
    kconv_all<<<19712, 256, 0, stream>>>(x, Wg1, Wdr, Wdi, Wg2, xb, Bct, B2t);

    // GEMM (gate GEMM2 fused into mat0 epilogue)
    if (drv_bf16)
        k1_8p<true><<<dim3(BT_/256, GN/256), 512, 0, stream>>>(
            xb, Bct, B2t, bg1, bg2, bdr, bdi, omgu, drvb, out);
    else
        k1_8p<false><<<dim3(BT_/256, GN/256), 512, 0, stream>>>(
            xb, Bct, B2t, bg1, bg2, bdr, bdi, omgu, drvb, out);

    // scan
    if (drv_bf16) {
        k3a_chunk<true><<<B_*S_*CHUNKS, 128, 0, stream>>>(omgu, drvb, out, summ, sc);
        k3b_scan       <<<(B_*S_*D_)/2, 256, 0, stream>>>(summ);
        k3c_final<true><<<B_*S_*CHUNKS, 128, 0, stream>>>(omgu, drvb, out, out, summ, sc);
    } else {
        k3a_chunk<false><<<B_*S_*CHUNKS, 128, 0, stream>>>(omgu, drvb, out, summ, sc);
        k3b_scan        <<<(B_*S_*D_)/2, 256, 0, stream>>>(summ);
        k3c_final<false><<<B_*S_*CHUNKS, 128, 0, stream>>>(omgu, drvb, out, out, summ, sc);
    }
}